// Round 3
// baseline (147.674 us; speedup 1.0000x reference)
//
#include <hip/hip_runtime.h>
#include <hip/hip_bf16.h>
#include <math.h>

// Problem constants (B,S,R,A,DW,DR) = (64,32,128,64,512,512)
#define B_  64
#define S_  32
#define R_  128
#define A_  64
#define DW_ 512
#define DR_ 512

// tanh(x) = 1 - 2/(e^{2x}+1), fast v_rcp_f32 path (~1 ulp; fine vs fp32 ref).
__device__ __forceinline__ float fast_tanh(float x) {
    x = fminf(fmaxf(x, -15.0f), 15.0f);
    float e = __expf(2.0f * x);
    return fmaf(-2.0f, __builtin_amdgcn_rcpf(e + 1.0f), 1.0f);
}

// C[M,N] = A[M,K] @ Bm[N,K]^T + bias1[N] (+ bias2[N]) (+ rowv[m]*colv[n])
// 64x64 tile, K-step 16, 256 threads, 4x4 micro-tile. Smem stored k-major so
// inner-loop reads are float4 (ds_read_b128); A-reads broadcast 16-way and
// B-reads 4-way (same-address lanes are free), so the loop is VALU-bound.
// Two GEMMs fused into one dispatch: blockIdx.z selects the parameter set.
__global__ __launch_bounds__(256) void gemm_dual_kernel(
    // z == 0: u = QV @ Wq^T + bq + bc + cov*Wc
    const float* __restrict__ A0, const float* __restrict__ B0, float* __restrict__ C0,
    int M0, int N0, int K0,
    const float* __restrict__ bias1_0, const float* __restrict__ bias2_0,
    const float* __restrict__ rowv0, const float* __restrict__ colv0,
    // z == 1: rp = rel @ Wr^T + br
    const float* __restrict__ A1, const float* __restrict__ B1, float* __restrict__ C1,
    int M1, int N1, int K1,
    const float* __restrict__ bias1_1)
{
    const int z = blockIdx.z;
    const float* Am; const float* Bm; float* C;
    const float *bias1, *bias2, *rowv, *colv;
    int M, N, K;
    if (z == 0) {
        Am = A0; Bm = B0; C = C0; M = M0; N = N0; K = K0;
        bias1 = bias1_0; bias2 = bias2_0; rowv = rowv0; colv = colv0;
    } else {
        Am = A1; Bm = B1; C = C1; M = M1; N = N1; K = K1;
        bias1 = bias1_1; bias2 = nullptr; rowv = nullptr; colv = nullptr;
    }

    const int bm = blockIdx.x * 64;
    const int bn = blockIdx.y * 64;
    if (bm >= M || bn >= N) return;   // z==1 uses only a 2x8 sub-grid

    __shared__ float As[16][64];
    __shared__ float Bs[16][64];
    const int tid = threadIdx.x;
    const int tr = tid >> 4;          // 0..15 (row group)
    const int tc = tid & 15;          // 0..15 (col group)
    const int lr = tid >> 2;          // staging row 0..63
    const int lk = (tid & 3) << 2;    // staging k offset {0,4,8,12}
    float acc[4][4] = {};

    for (int k0 = 0; k0 < K; k0 += 16) {
        float4 av = *(const float4*)&Am[(size_t)(bm + lr) * K + k0 + lk];
        float4 bv = *(const float4*)&Bm[(size_t)(bn + lr) * K + k0 + lk];
        __syncthreads();
        As[lk + 0][lr] = av.x; As[lk + 1][lr] = av.y;
        As[lk + 2][lr] = av.z; As[lk + 3][lr] = av.w;
        Bs[lk + 0][lr] = bv.x; Bs[lk + 1][lr] = bv.y;
        Bs[lk + 2][lr] = bv.z; Bs[lk + 3][lr] = bv.w;
        __syncthreads();
        #pragma unroll
        for (int kk = 0; kk < 16; ++kk) {
            float4 a4 = *(const float4*)&As[kk][tr << 2];
            float4 b4 = *(const float4*)&Bs[kk][tc << 2];
            float aa[4] = {a4.x, a4.y, a4.z, a4.w};
            float bb[4] = {b4.x, b4.y, b4.z, b4.w};
            #pragma unroll
            for (int i = 0; i < 4; ++i)
                #pragma unroll
                for (int j = 0; j < 4; ++j)
                    acc[i][j] = fmaf(aa[i], bb[j], acc[i][j]);
        }
    }

    #pragma unroll
    for (int i = 0; i < 4; ++i) {
        const int m = bm + (tr << 2) + i;
        const float rv = rowv ? rowv[m] : 0.0f;
        float4 o;
        float* op = &o.x;
        #pragma unroll
        for (int j = 0; j < 4; ++j) {
            const int n = bn + (tc << 2) + j;
            float v = acc[i][j] + bias1[n];
            if (bias2) v += bias2[n];
            if (rowv)  v += rv * colv[n];
            op[j] = v;
        }
        *(float4*)&C[(size_t)m * N + bn + (tc << 2)] = o;
    }
}

// One block per (b,a). 4 waves: wave w computes scores for s = w*8..w*8+7
// (lane-register rp/Watt, 8 d's per lane, 64-lane shuffle reduce), then a
// 32-lane softmax, then coalesced ctx accumulation over qv.
// d-permutation: lane covers float4 chunks {v*64+lane : v=0,1}; each wave-wide
// load instruction is one contiguous 1KB segment. Score sum is invariant to
// the d-permutation (u, rp, watt all use the same one).
__global__ __launch_bounds__(256) void attn_kernel(
    const float* __restrict__ u,      // [B*S, DR]  (qp + bq + cov*Wc + bc)
    const float* __restrict__ rp,     // [R, DR]    (rel@Wr^T + br)
    const float* __restrict__ watt,   // [DR]
    const float* __restrict__ battp,  // [1]
    const float* __restrict__ qv,     // [B*S, DW]
    const unsigned char* __restrict__ mask, // [B*S] (bool; true = padding)
    const int* __restrict__ rspace,   // [B*A]
    float* __restrict__ out,          // [B*A, DW]
    float* __restrict__ alpha_out)    // [B*A, S]
{
    const int ba   = blockIdx.x;      // b*A + a
    const int b    = ba >> 6;         // /A_
    const int tid  = threadIdx.x;
    const int lane = tid & 63;
    const int wave = tid >> 6;
    const int r    = rspace[ba];

    __shared__ float s_scores[S_];
    __shared__ float s_alpha[S_];

    // Stage rp[r,:] and Watt into registers (contiguous per-instruction)
    float rpv[8], wav[8];
    const float4* rp4 = (const float4*)(rp + (size_t)r * DR_);
    const float4* wa4 = (const float4*)watt;
    #pragma unroll
    for (int v = 0; v < 2; ++v) {
        float4 t = rp4[v * 64 + lane];
        float4 w = wa4[v * 64 + lane];
        rpv[v*4+0] = t.x; rpv[v*4+1] = t.y; rpv[v*4+2] = t.z; rpv[v*4+3] = t.w;
        wav[v*4+0] = w.x; wav[v*4+1] = w.y; wav[v*4+2] = w.z; wav[v*4+3] = w.w;
    }
    const float batt = battp[0];

    #pragma unroll
    for (int si = 0; si < 8; ++si) {
        const int s = (wave << 3) + si;
        const float4* u4 = (const float4*)(u + ((size_t)b * S_ + s) * DR_);
        float acc = 0.0f;
        #pragma unroll
        for (int v = 0; v < 2; ++v) {
            float4 uu = u4[v * 64 + lane];
            acc += wav[v*4+0] * fast_tanh(uu.x + rpv[v*4+0]);
            acc += wav[v*4+1] * fast_tanh(uu.y + rpv[v*4+1]);
            acc += wav[v*4+2] * fast_tanh(uu.z + rpv[v*4+2]);
            acc += wav[v*4+3] * fast_tanh(uu.w + rpv[v*4+3]);
        }
        #pragma unroll
        for (int off = 32; off > 0; off >>= 1)
            acc += __shfl_xor(acc, off);
        if (lane == 0) s_scores[s] = acc + batt;
    }
    __syncthreads();

    if (tid < S_) {
        float sc = s_scores[tid];
        if (mask[b * S_ + tid]) sc = -INFINITY;
        float m = sc;
        #pragma unroll
        for (int off = 16; off > 0; off >>= 1)
            m = fmaxf(m, __shfl_xor(m, off));
        float e = __expf(sc - m);
        float sum = e;
        #pragma unroll
        for (int off = 16; off > 0; off >>= 1)
            sum += __shfl_xor(sum, off);
        float al = e / sum;
        s_alpha[tid] = al;
        alpha_out[(size_t)ba * S_ + tid] = al;
    }
    __syncthreads();

    // ctx: out[ba, w] = sum_s alpha[s] * qv[b, s, w]; thread handles w = tid*2, tid*2+1
    float2 acc2 = make_float2(0.0f, 0.0f);
    const float* qb = qv + (size_t)b * S_ * DW_;
    #pragma unroll 4
    for (int s = 0; s < S_; ++s) {
        const float al = s_alpha[s];
        float2 q = *(const float2*)&qb[s * DW_ + tid * 2];
        acc2.x = fmaf(al, q.x, acc2.x);
        acc2.y = fmaf(al, q.y, acc2.y);
    }
    *(float2*)&out[(size_t)ba * DW_ + tid * 2] = acc2;
}

extern "C" void kernel_launch(void* const* d_in, const int* in_sizes, int n_in,
                              void* d_out, int out_size, void* d_ws, size_t ws_size,
                              hipStream_t stream) {
    const float*         qv   = (const float*)d_in[0];          // [B,S,DW]
    const unsigned char* mask = (const unsigned char*)d_in[1];  // [B,S] bool
    const int*           rsp  = (const int*)d_in[2];            // [B,A]
    const float*         cov  = (const float*)d_in[3];          // [B,S]
    const float*         rel  = (const float*)d_in[4];          // [R,DR]
    const float*         Wq   = (const float*)d_in[5];          // [DR,DW]
    const float*         bq   = (const float*)d_in[6];          // [DR]
    const float*         Wr   = (const float*)d_in[7];          // [DR,DR]
    const float*         br   = (const float*)d_in[8];          // [DR]
    const float*         Wc   = (const float*)d_in[9];          // [DR,1] -> [DR]
    const float*         bc   = (const float*)d_in[10];         // [DR]
    const float*         Watt = (const float*)d_in[11];         // [1,DR] -> [DR]
    const float*         batt = (const float*)d_in[12];         // [1]

    // Workspace: u [B*S,DR] = 4 MB, rp [R,DR] = 256 KB (total 4.25 MB)
    float* u  = (float*)d_ws;
    float* rp = u + (size_t)B_ * S_ * DR_;

    float* out       = (float*)d_out;                 // [B,A,DW]
    float* alpha_out = out + (size_t)B_ * A_ * DW_;   // [B,A,S]

    dim3 blk(256);

    // Both GEMMs in one dispatch (z=0: u, z=1: rp; z=1 early-outs past 2x8)
    gemm_dual_kernel<<<dim3((B_ * S_) / 64, DR_ / 64, 2), blk, 0, stream>>>(
        qv, Wq, u, B_ * S_, DR_, DW_, bq, bc, cov, Wc,
        rel, Wr, rp, R_, DR_, DR_, br);

    // fused per-(b,a) attention + gather
    attn_kernel<<<dim3(B_ * A_), blk, 0, stream>>>(
        u, rp, Watt, batt, qv, mask, rsp, out, alpha_out);
}

// Round 5
// 127.492 us; speedup vs baseline: 1.1583x; 1.1583x over previous
//
#include <hip/hip_runtime.h>
#include <hip/hip_bf16.h>
#include <math.h>

// Problem constants (B,S,R,A,DW,DR) = (64,32,128,64,512,512)
#define B_  64
#define S_  32
#define R_  128
#define A_  64
#define DW_ 512
#define DR_ 512

typedef __attribute__((ext_vector_type(8))) short short8;   // 8 bf16 (4 VGPRs)
typedef __attribute__((ext_vector_type(4))) float f32x4;    // MFMA accumulator

// tanh(x) = 1 - 2/(e^{2x}+1), fast v_rcp_f32 path (~1 ulp; fine vs fp32 ref).
__device__ __forceinline__ float fast_tanh(float x) {
    x = fminf(fmaxf(x, -15.0f), 15.0f);
    float e = __expf(2.0f * x);
    return fmaf(-2.0f, __builtin_amdgcn_rcpf(e + 1.0f), 1.0f);
}

__device__ __forceinline__ unsigned short bf16_rn(float x) {
    union { float f; unsigned u; } v; v.f = x;
    unsigned r = v.u + 0x7FFF + ((v.u >> 16) & 1);
    return (unsigned short)(r >> 16);
}
__device__ __forceinline__ float bf16_to_f(unsigned short h) {
    union { unsigned u; float f; } v; v.u = ((unsigned)h) << 16;
    return v.f;
}

// Swizzled LDS index for a [64][32] bf16 tile (4 chunks of 8 bf16 per row).
// Access pattern (16 rows x 4 chunks per wave instr) is bandwidth-minimal and
// evenly distributed across banks; addresses are loop-invariant (hoisted).
__device__ __forceinline__ int swz(int row, int chunk) {
    return row * 32 + ((chunk ^ ((row >> 1) & 3)) << 3);
}

// C[M,N] = A[M,K] @ Bm[N,K]^T + bias1[N] (+ bias2[N]) (+ rowv[m]*colv[n])
// Split-bf16 MFMA: each fp32 a = hi + lo (two bf16); A*B ~ hi*hi + hi*lo + lo*hi
// keeps fp32-level accuracy (residual ~2^-17 rel) at MFMA speed.
// 64x64 tile, BK=32, 256 threads = 4 waves in 2x2, each wave 2x2 quadrants of
// mfma_f32_16x16x32_bf16. Register prefetch of next K-tile behind MFMA phase.
// Two GEMMs in one dispatch: blockIdx.z selects the parameter set.
__global__ __launch_bounds__(256) void gemm_dual_kernel(
    // z == 0: u = QV @ Wq^T + bq + bc + cov*Wc
    const float* __restrict__ A0, const float* __restrict__ B0, float* __restrict__ C0,
    int M0, int N0, int K0,
    const float* __restrict__ bias1_0, const float* __restrict__ bias2_0,
    const float* __restrict__ rowv0, const float* __restrict__ colv0,
    // z == 1: rp = rel @ Wr^T + br
    const float* __restrict__ A1, const float* __restrict__ B1, float* __restrict__ C1,
    int M1, int N1, int K1,
    const float* __restrict__ bias1_1)
{
    const int z = blockIdx.z;
    const float* Am; const float* Bm; float* C;
    const float *bias1, *bias2, *rowv, *colv;
    int M, N, K;
    if (z == 0) {
        Am = A0; Bm = B0; C = C0; M = M0; N = N0; K = K0;
        bias1 = bias1_0; bias2 = bias2_0; rowv = rowv0; colv = colv0;
    } else {
        Am = A1; Bm = B1; C = C1; M = M1; N = N1; K = K1;
        bias1 = bias1_1; bias2 = nullptr; rowv = nullptr; colv = nullptr;
    }

    const int bm = blockIdx.x * 64;
    const int bn = blockIdx.y * 64;
    if (bm >= M || bn >= N) return;   // z==1 uses only a 2x8 sub-grid

    __shared__ unsigned short Ahi[64 * 32], Alo[64 * 32];
    __shared__ unsigned short Bhi[64 * 32], Blo[64 * 32];

    const int tid  = threadIdx.x;
    const int l    = tid & 63;
    const int w    = tid >> 6;
    const int wr   = w >> 1;          // wave row (0..1)
    const int wc   = w & 1;           // wave col (0..1)
    const int fr   = l & 15;          // frag row/col within 16x16
    const int fc   = l >> 4;          // frag k-chunk (0..3)
    const int srow = tid >> 2;        // staging row 0..63
    const int sch  = tid & 3;         // staging k-chunk 0..3 (8 fp32 each)

    f32x4 acc[2][2] = {};

    // prefetch registers for the current K-step
    float4 ra0, ra1, rb0, rb1;
    {
        const size_t arow = (size_t)(bm + srow) * K + sch * 8;
        const size_t brow = (size_t)(bn + srow) * K + sch * 8;
        ra0 = *(const float4*)&Am[arow];     ra1 = *(const float4*)&Am[arow + 4];
        rb0 = *(const float4*)&Bm[brow];     rb1 = *(const float4*)&Bm[brow + 4];
    }

    const int nsteps = K >> 5;        // K/32
    for (int s = 0; s < nsteps; ++s) {
        // convert current regs to hi/lo bf16
        short8 ahi, alo, bhi, blo;
        {
            float af[8] = {ra0.x, ra0.y, ra0.z, ra0.w, ra1.x, ra1.y, ra1.z, ra1.w};
            float bf[8] = {rb0.x, rb0.y, rb0.z, rb0.w, rb1.x, rb1.y, rb1.z, rb1.w};
            #pragma unroll
            for (int e = 0; e < 8; ++e) {
                unsigned short h = bf16_rn(af[e]);
                ahi[e] = (short)h;
                alo[e] = (short)bf16_rn(af[e] - bf16_to_f(h));
                unsigned short g = bf16_rn(bf[e]);
                bhi[e] = (short)g;
                blo[e] = (short)bf16_rn(bf[e] - bf16_to_f(g));
            }
        }
        __syncthreads();              // prior frag reads done before overwrite
        *(short8*)&Ahi[swz(srow, sch)] = ahi;
        *(short8*)&Alo[swz(srow, sch)] = alo;
        *(short8*)&Bhi[swz(srow, sch)] = bhi;
        *(short8*)&Blo[swz(srow, sch)] = blo;
        __syncthreads();

        if (s + 1 < nsteps) {         // issue next-step loads; latency hides under MFMA
            const int k0 = (s + 1) << 5;
            const size_t arow = (size_t)(bm + srow) * K + k0 + sch * 8;
            const size_t brow = (size_t)(bn + srow) * K + k0 + sch * 8;
            ra0 = *(const float4*)&Am[arow];     ra1 = *(const float4*)&Am[arow + 4];
            rb0 = *(const float4*)&Bm[brow];     rb1 = *(const float4*)&Bm[brow + 4];
        }

        // frag reads (loop-invariant addresses) + 12 MFMA
        short8 fahi[2], falo[2], fbhi[2], fblo[2];
        #pragma unroll
        for (int i = 0; i < 2; ++i) {
            const int r = wr * 32 + i * 16 + fr;
            fahi[i] = *(const short8*)&Ahi[swz(r, fc)];
            falo[i] = *(const short8*)&Alo[swz(r, fc)];
            const int c = wc * 32 + i * 16 + fr;
            fbhi[i] = *(const short8*)&Bhi[swz(c, fc)];
            fblo[i] = *(const short8*)&Blo[swz(c, fc)];
        }
        #pragma unroll
        for (int i = 0; i < 2; ++i)
            #pragma unroll
            for (int j = 0; j < 2; ++j) {
                acc[i][j] = __builtin_amdgcn_mfma_f32_16x16x32_bf16(fahi[i], fbhi[j], acc[i][j], 0, 0, 0);
                acc[i][j] = __builtin_amdgcn_mfma_f32_16x16x32_bf16(fahi[i], fblo[j], acc[i][j], 0, 0, 0);
                acc[i][j] = __builtin_amdgcn_mfma_f32_16x16x32_bf16(falo[i], fbhi[j], acc[i][j], 0, 0, 0);
            }
    }

    // Epilogue. C/D layout (m89): col = l&15, row = (l>>4)*4 + reg.
    #pragma unroll
    for (int i = 0; i < 2; ++i)
        #pragma unroll
        for (int j = 0; j < 2; ++j) {
            const int n  = bn + wc * 32 + j * 16 + fr;
            const float b1 = bias1[n];
            const float b2 = bias2 ? bias2[n] : 0.0f;
            const float cv = colv ? colv[n] : 0.0f;
            #pragma unroll
            for (int reg = 0; reg < 4; ++reg) {
                const int m = bm + wr * 32 + i * 16 + fc * 4 + reg;
                float v = acc[i][j][reg] + b1 + b2;
                if (rowv) v += rowv[m] * cv;
                C[(size_t)m * N + n] = v;
            }
        }
}

// One block per (b,a). 4 waves: wave w computes scores for s = w*8..w*8+7
// (lane-register rp/Watt, 8 d's per lane, 64-lane shuffle reduce), then a
// 32-lane softmax, then coalesced ctx accumulation over qv.
// d-permutation: lane covers float4 chunks {v*64+lane : v=0,1}; each wave-wide
// load instruction is one contiguous 1KB segment. Score sum is invariant to
// the d-permutation (u, rp, watt all use the same one).
__global__ __launch_bounds__(256) void attn_kernel(
    const float* __restrict__ u,      // [B*S, DR]  (qp + bq + cov*Wc + bc)
    const float* __restrict__ rp,     // [R, DR]    (rel@Wr^T + br)
    const float* __restrict__ watt,   // [DR]
    const float* __restrict__ battp,  // [1]
    const float* __restrict__ qv,     // [B*S, DW]
    const unsigned char* __restrict__ mask, // [B*S] (bool; true = padding)
    const int* __restrict__ rspace,   // [B*A]
    float* __restrict__ out,          // [B*A, DW]
    float* __restrict__ alpha_out)    // [B*A, S]
{
    const int ba   = blockIdx.x;      // b*A + a
    const int b    = ba >> 6;         // /A_
    const int tid  = threadIdx.x;
    const int lane = tid & 63;
    const int wave = tid >> 6;
    const int r    = rspace[ba];

    __shared__ float s_scores[S_];
    __shared__ float s_alpha[S_];

    // Stage rp[r,:] and Watt into registers (contiguous per-instruction)
    float rpv[8], wav[8];
    const float4* rp4 = (const float4*)(rp + (size_t)r * DR_);
    const float4* wa4 = (const float4*)watt;
    #pragma unroll
    for (int v = 0; v < 2; ++v) {
        float4 t = rp4[v * 64 + lane];
        float4 w = wa4[v * 64 + lane];
        rpv[v*4+0] = t.x; rpv[v*4+1] = t.y; rpv[v*4+2] = t.z; rpv[v*4+3] = t.w;
        wav[v*4+0] = w.x; wav[v*4+1] = w.y; wav[v*4+2] = w.z; wav[v*4+3] = w.w;
    }
    const float batt = battp[0];

    #pragma unroll
    for (int si = 0; si < 8; ++si) {
        const int s = (wave << 3) + si;
        const float4* u4 = (const float4*)(u + ((size_t)b * S_ + s) * DR_);
        float acc = 0.0f;
        #pragma unroll
        for (int v = 0; v < 2; ++v) {
            float4 uu = u4[v * 64 + lane];
            acc += wav[v*4+0] * fast_tanh(uu.x + rpv[v*4+0]);
            acc += wav[v*4+1] * fast_tanh(uu.y + rpv[v*4+1]);
            acc += wav[v*4+2] * fast_tanh(uu.z + rpv[v*4+2]);
            acc += wav[v*4+3] * fast_tanh(uu.w + rpv[v*4+3]);
        }
        #pragma unroll
        for (int off = 32; off > 0; off >>= 1)
            acc += __shfl_xor(acc, off);
        if (lane == 0) s_scores[s] = acc + batt;
    }
    __syncthreads();

    if (tid < S_) {
        float sc = s_scores[tid];
        if (mask[b * S_ + tid]) sc = -INFINITY;
        float m = sc;
        #pragma unroll
        for (int off = 16; off > 0; off >>= 1)
            m = fmaxf(m, __shfl_xor(m, off));
        float e = __expf(sc - m);
        float sum = e;
        #pragma unroll
        for (int off = 16; off > 0; off >>= 1)
            sum += __shfl_xor(sum, off);
        float al = e / sum;
        s_alpha[tid] = al;
        alpha_out[(size_t)ba * S_ + tid] = al;
    }
    __syncthreads();

    // ctx: out[ba, w] = sum_s alpha[s] * qv[b, s, w]; thread handles w = tid*2, tid*2+1
    float2 acc2 = make_float2(0.0f, 0.0f);
    const float* qb = qv + (size_t)b * S_ * DW_;
    #pragma unroll 4
    for (int s = 0; s < S_; ++s) {
        const float al = s_alpha[s];
        float2 q = *(const float2*)&qb[s * DW_ + tid * 2];
        acc2.x = fmaf(al, q.x, acc2.x);
        acc2.y = fmaf(al, q.y, acc2.y);
    }
    *(float2*)&out[(size_t)ba * DW_ + tid * 2] = acc2;
}

extern "C" void kernel_launch(void* const* d_in, const int* in_sizes, int n_in,
                              void* d_out, int out_size, void* d_ws, size_t ws_size,
                              hipStream_t stream) {
    const float*         qv   = (const float*)d_in[0];          // [B,S,DW]
    const unsigned char* mask = (const unsigned char*)d_in[1];  // [B,S] bool
    const int*           rsp  = (const int*)d_in[2];            // [B,A]
    const float*         cov  = (const float*)d_in[3];          // [B,S]
    const float*         rel  = (const float*)d_in[4];          // [R,DR]
    const float*         Wq   = (const float*)d_in[5];          // [DR,DW]
    const float*         bq   = (const float*)d_in[6];          // [DR]
    const float*         Wr   = (const float*)d_in[7];          // [DR,DR]
    const float*         br   = (const float*)d_in[8];          // [DR]
    const float*         Wc   = (const float*)d_in[9];          // [DR,1] -> [DR]
    const float*         bc   = (const float*)d_in[10];         // [DR]
    const float*         Watt = (const float*)d_in[11];         // [1,DR] -> [DR]
    const float*         batt = (const float*)d_in[12];         // [1]

    // Workspace: u [B*S,DR] = 4 MB, rp [R,DR] = 256 KB (total 4.25 MB)
    float* u  = (float*)d_ws;
    float* rp = u + (size_t)B_ * S_ * DR_;

    float* out       = (float*)d_out;                 // [B,A,DW]
    float* alpha_out = out + (size_t)B_ * A_ * DW_;   // [B,A,S]

    dim3 blk(256);

    // Both GEMMs in one dispatch (z=0: u, z=1: rp; z=1 early-outs past 2x8)
    gemm_dual_kernel<<<dim3((B_ * S_) / 64, DR_ / 64, 2), blk, 0, stream>>>(
        qv, Wq, u, B_ * S_, DR_, DW_, bq, bc, cov, Wc,
        rel, Wr, rp, R_, DR_, DR_, br);

    // fused per-(b,a) attention + gather
    attn_kernel<<<dim3(B_ * A_), blk, 0, stream>>>(
        u, rp, Watt, batt, qv, mask, rsp, out, alpha_out);
}

// Round 6
// 120.185 us; speedup vs baseline: 1.2287x; 1.0608x over previous
//
#include <hip/hip_runtime.h>
#include <hip/hip_bf16.h>
#include <math.h>

// Problem constants (B,S,R,A,DW,DR) = (64,32,128,64,512,512)
#define B_  64
#define S_  32
#define R_  128
#define A_  64
#define DW_ 512
#define DR_ 512

typedef __attribute__((ext_vector_type(8))) short short8;   // 8 bf16 (4 VGPRs)
typedef __attribute__((ext_vector_type(4))) float f32x4;    // MFMA accumulator

__device__ __forceinline__ unsigned short bf16_rn(float x) {
    union { float f; unsigned u; } v; v.f = x;
    unsigned r = v.u + 0x7FFF + ((v.u >> 16) & 1);
    return (unsigned short)(r >> 16);
}
__device__ __forceinline__ float bf16_to_f(unsigned short h) {
    union { unsigned u; float f; } v; v.u = ((unsigned)h) << 16;
    return v.f;
}

// Swizzled LDS index for a [64][32] bf16 tile (4 chunks of 8 bf16 per row).
__device__ __forceinline__ int swz(int row, int chunk) {
    return row * 32 + ((chunk ^ ((row >> 1) & 3)) << 3);
}

// C[M,N] = A[M,K] @ Bm[N,K]^T + bias1[N] (+ bias2[N]) (+ rowv[m]*colv[n])
// Split-bf16 MFMA (validated round 5: absmax 0.00195). Byte-identical to r5.
__global__ __launch_bounds__(256) void gemm_dual_kernel(
    const float* __restrict__ A0, const float* __restrict__ B0, float* __restrict__ C0,
    int M0, int N0, int K0,
    const float* __restrict__ bias1_0, const float* __restrict__ bias2_0,
    const float* __restrict__ rowv0, const float* __restrict__ colv0,
    const float* __restrict__ A1, const float* __restrict__ B1, float* __restrict__ C1,
    int M1, int N1, int K1,
    const float* __restrict__ bias1_1)
{
    const int z = blockIdx.z;
    const float* Am; const float* Bm; float* C;
    const float *bias1, *bias2, *rowv, *colv;
    int M, N, K;
    if (z == 0) {
        Am = A0; Bm = B0; C = C0; M = M0; N = N0; K = K0;
        bias1 = bias1_0; bias2 = bias2_0; rowv = rowv0; colv = colv0;
    } else {
        Am = A1; Bm = B1; C = C1; M = M1; N = N1; K = K1;
        bias1 = bias1_1; bias2 = nullptr; rowv = nullptr; colv = nullptr;
    }

    const int bm = blockIdx.x * 64;
    const int bn = blockIdx.y * 64;
    if (bm >= M || bn >= N) return;

    __shared__ unsigned short Ahi[64 * 32], Alo[64 * 32];
    __shared__ unsigned short Bhi[64 * 32], Blo[64 * 32];

    const int tid  = threadIdx.x;
    const int l    = tid & 63;
    const int w    = tid >> 6;
    const int wr   = w >> 1;
    const int wc   = w & 1;
    const int fr   = l & 15;
    const int fc   = l >> 4;
    const int srow = tid >> 2;
    const int sch  = tid & 3;

    f32x4 acc[2][2] = {};

    float4 ra0, ra1, rb0, rb1;
    {
        const size_t arow = (size_t)(bm + srow) * K + sch * 8;
        const size_t brow = (size_t)(bn + srow) * K + sch * 8;
        ra0 = *(const float4*)&Am[arow];     ra1 = *(const float4*)&Am[arow + 4];
        rb0 = *(const float4*)&Bm[brow];     rb1 = *(const float4*)&Bm[brow + 4];
    }

    const int nsteps = K >> 5;
    for (int s = 0; s < nsteps; ++s) {
        short8 ahi, alo, bhi, blo;
        {
            float af[8] = {ra0.x, ra0.y, ra0.z, ra0.w, ra1.x, ra1.y, ra1.z, ra1.w};
            float bf[8] = {rb0.x, rb0.y, rb0.z, rb0.w, rb1.x, rb1.y, rb1.z, rb1.w};
            #pragma unroll
            for (int e = 0; e < 8; ++e) {
                unsigned short h = bf16_rn(af[e]);
                ahi[e] = (short)h;
                alo[e] = (short)bf16_rn(af[e] - bf16_to_f(h));
                unsigned short g = bf16_rn(bf[e]);
                bhi[e] = (short)g;
                blo[e] = (short)bf16_rn(bf[e] - bf16_to_f(g));
            }
        }
        __syncthreads();
        *(short8*)&Ahi[swz(srow, sch)] = ahi;
        *(short8*)&Alo[swz(srow, sch)] = alo;
        *(short8*)&Bhi[swz(srow, sch)] = bhi;
        *(short8*)&Blo[swz(srow, sch)] = blo;
        __syncthreads();

        if (s + 1 < nsteps) {
            const int k0 = (s + 1) << 5;
            const size_t arow = (size_t)(bm + srow) * K + k0 + sch * 8;
            const size_t brow = (size_t)(bn + srow) * K + k0 + sch * 8;
            ra0 = *(const float4*)&Am[arow];     ra1 = *(const float4*)&Am[arow + 4];
            rb0 = *(const float4*)&Bm[brow];     rb1 = *(const float4*)&Bm[brow + 4];
        }

        short8 fahi[2], falo[2], fbhi[2], fblo[2];
        #pragma unroll
        for (int i = 0; i < 2; ++i) {
            const int r = wr * 32 + i * 16 + fr;
            fahi[i] = *(const short8*)&Ahi[swz(r, fc)];
            falo[i] = *(const short8*)&Alo[swz(r, fc)];
            const int c = wc * 32 + i * 16 + fr;
            fbhi[i] = *(const short8*)&Bhi[swz(c, fc)];
            fblo[i] = *(const short8*)&Blo[swz(c, fc)];
        }
        #pragma unroll
        for (int i = 0; i < 2; ++i)
            #pragma unroll
            for (int j = 0; j < 2; ++j) {
                acc[i][j] = __builtin_amdgcn_mfma_f32_16x16x32_bf16(fahi[i], fbhi[j], acc[i][j], 0, 0, 0);
                acc[i][j] = __builtin_amdgcn_mfma_f32_16x16x32_bf16(fahi[i], fblo[j], acc[i][j], 0, 0, 0);
                acc[i][j] = __builtin_amdgcn_mfma_f32_16x16x32_bf16(falo[i], fbhi[j], acc[i][j], 0, 0, 0);
            }
    }

    #pragma unroll
    for (int i = 0; i < 2; ++i)
        #pragma unroll
        for (int j = 0; j < 2; ++j) {
            const int n  = bn + wc * 32 + j * 16 + fr;
            const float b1 = bias1[n];
            const float b2 = bias2 ? bias2[n] : 0.0f;
            const float cv = colv ? colv[n] : 0.0f;
            #pragma unroll
            for (int reg = 0; reg < 4; ++reg) {
                const int m = bm + wr * 32 + i * 16 + fc * 4 + reg;
                float v = acc[i][j][reg] + b1 + b2;
                if (rowv) v += rowv[m] * cv;
                C[(size_t)m * N + n] = v;
            }
        }
}

// One block per (b, group of 4 a's). Score math uses the folded-tanh identity:
//   sum_d wa_d * tanh(u_d + rp_d) = sum_d wa_d - 2 * sum_d wa_d / (exp2(K2*u_d + rp2_d) + 1)
// with K2 = 2*log2(e), rp2 = K2*rp precomputed -> 3 VALU + 2 TRANS per element
// (no clamp needed: exp2->inf => rcp->0 => tanh=1 exact; exp2->0 => tanh=-1).
// u/qv rows are loaded once and reused across the 4 a's (4x less cache traffic).
__global__ __launch_bounds__(256) void attn_kernel(
    const float* __restrict__ u,      // [B*S, DR]
    const float* __restrict__ rp,     // [R, DR]
    const float* __restrict__ watt,   // [DR]
    const float* __restrict__ battp,  // [1]
    const float* __restrict__ qv,     // [B*S, DW]
    const unsigned char* __restrict__ mask, // [B*S]
    const int* __restrict__ rspace,   // [B*A]
    float* __restrict__ out,          // [B*A, DW]
    float* __restrict__ alpha_out)    // [B*A, S]
{
    const int blk  = blockIdx.x;      // b*16 + grp
    const int b    = blk >> 4;
    const int ba0  = b * A_ + ((blk & 15) << 2);  // first of 4 consecutive a's
    const int tid  = threadIdx.x;
    const int lane = tid & 63;
    const int wave = tid >> 6;

    const float K2 = 2.8853900817779268f;  // 2*log2(e)

    __shared__ float s_scores[4][S_];
    __shared__ float s_alpha[4][S_];

    // Stage Watt and the 4 rp rows (pre-scaled by K2) into registers.
    float wav[8], rp2[4][8];
    {
        const float4* wa4 = (const float4*)watt;
        #pragma unroll
        for (int v = 0; v < 2; ++v) {
            float4 w = wa4[v * 64 + lane];
            wav[v*4+0] = w.x; wav[v*4+1] = w.y; wav[v*4+2] = w.z; wav[v*4+3] = w.w;
        }
        #pragma unroll
        for (int g = 0; g < 4; ++g) {
            const float4* rp4 = (const float4*)(rp + (size_t)rspace[ba0 + g] * DR_);
            #pragma unroll
            for (int v = 0; v < 2; ++v) {
                float4 t = rp4[v * 64 + lane];
                rp2[g][v*4+0] = t.x * K2; rp2[g][v*4+1] = t.y * K2;
                rp2[g][v*4+2] = t.z * K2; rp2[g][v*4+3] = t.w * K2;
            }
        }
    }
    const float batt = battp[0];

    // swa = sum_d wa_d (reduced across the wave once)
    float swa = wav[0] + wav[1] + wav[2] + wav[3] + wav[4] + wav[5] + wav[6] + wav[7];
    #pragma unroll
    for (int off = 32; off > 0; off >>= 1)
        swa += __shfl_xor(swa, off);

    // Scores: wave w handles s = w*8 .. w*8+7 for all 4 a's.
    #pragma unroll
    for (int si = 0; si < 8; ++si) {
        const int s = (wave << 3) + si;
        const float4* u4 = (const float4*)(u + ((size_t)b * S_ + s) * DR_);
        float uu[8];
        #pragma unroll
        for (int v = 0; v < 2; ++v) {
            float4 t = u4[v * 64 + lane];
            uu[v*4+0] = t.x; uu[v*4+1] = t.y; uu[v*4+2] = t.z; uu[v*4+3] = t.w;
        }
        float ac0 = 0.0f, ac1 = 0.0f, ac2 = 0.0f, ac3 = 0.0f;
        #pragma unroll
        for (int e = 0; e < 8; ++e) {
            const float ue = uu[e];
            const float we = wav[e];
            float z0 = __builtin_amdgcn_exp2f(fmaf(ue, K2, rp2[0][e]));
            float z1 = __builtin_amdgcn_exp2f(fmaf(ue, K2, rp2[1][e]));
            float z2 = __builtin_amdgcn_exp2f(fmaf(ue, K2, rp2[2][e]));
            float z3 = __builtin_amdgcn_exp2f(fmaf(ue, K2, rp2[3][e]));
            ac0 = fmaf(we, __builtin_amdgcn_rcpf(z0 + 1.0f), ac0);
            ac1 = fmaf(we, __builtin_amdgcn_rcpf(z1 + 1.0f), ac1);
            ac2 = fmaf(we, __builtin_amdgcn_rcpf(z2 + 1.0f), ac2);
            ac3 = fmaf(we, __builtin_amdgcn_rcpf(z3 + 1.0f), ac3);
        }
        #pragma unroll
        for (int off = 32; off > 0; off >>= 1) {
            ac0 += __shfl_xor(ac0, off);
            ac1 += __shfl_xor(ac1, off);
            ac2 += __shfl_xor(ac2, off);
            ac3 += __shfl_xor(ac3, off);
        }
        if (lane == 0) {
            s_scores[0][s] = fmaf(-2.0f, ac0, swa) + batt;
            s_scores[1][s] = fmaf(-2.0f, ac1, swa) + batt;
            s_scores[2][s] = fmaf(-2.0f, ac2, swa) + batt;
            s_scores[3][s] = fmaf(-2.0f, ac3, swa) + batt;
        }
    }
    __syncthreads();

    // Softmax: 32-lane group per a (4 groups over tid 0..127). xor-offsets
    // 16..1 stay within each 32-lane half-wave.
    if (tid < 128) {
        const int g = tid >> 5;
        const int s = tid & 31;
        float sc = s_scores[g][s];
        if (mask[b * S_ + s]) sc = -INFINITY;
        float m = sc;
        #pragma unroll
        for (int off = 16; off > 0; off >>= 1)
            m = fmaxf(m, __shfl_xor(m, off));
        float e = __expf(sc - m);
        float sum = e;
        #pragma unroll
        for (int off = 16; off > 0; off >>= 1)
            sum += __shfl_xor(sum, off);
        float al = e / sum;
        s_alpha[g][s] = al;
        alpha_out[(size_t)(ba0 + g) * S_ + s] = al;
    }
    __syncthreads();

    // ctx: qv row loads shared across the 4 a's. Thread owns w = tid*2, tid*2+1.
    float2 acc[4] = {};
    const float* qb = qv + (size_t)b * S_ * DW_;
    #pragma unroll 4
    for (int s = 0; s < S_; ++s) {
        float2 q = *(const float2*)&qb[s * DW_ + tid * 2];
        #pragma unroll
        for (int g = 0; g < 4; ++g) {
            const float al = s_alpha[g][s];
            acc[g].x = fmaf(al, q.x, acc[g].x);
            acc[g].y = fmaf(al, q.y, acc[g].y);
        }
    }
    #pragma unroll
    for (int g = 0; g < 4; ++g)
        *(float2*)&out[(size_t)(ba0 + g) * DW_ + tid * 2] = acc[g];
}

extern "C" void kernel_launch(void* const* d_in, const int* in_sizes, int n_in,
                              void* d_out, int out_size, void* d_ws, size_t ws_size,
                              hipStream_t stream) {
    const float*         qv   = (const float*)d_in[0];          // [B,S,DW]
    const unsigned char* mask = (const unsigned char*)d_in[1];  // [B,S] bool
    const int*           rsp  = (const int*)d_in[2];            // [B,A]
    const float*         cov  = (const float*)d_in[3];          // [B,S]
    const float*         rel  = (const float*)d_in[4];          // [R,DR]
    const float*         Wq   = (const float*)d_in[5];          // [DR,DW]
    const float*         bq   = (const float*)d_in[6];          // [DR]
    const float*         Wr   = (const float*)d_in[7];          // [DR,DR]
    const float*         br   = (const float*)d_in[8];          // [DR]
    const float*         Wc   = (const float*)d_in[9];          // [DR,1] -> [DR]
    const float*         bc   = (const float*)d_in[10];         // [DR]
    const float*         Watt = (const float*)d_in[11];         // [1,DR] -> [DR]
    const float*         batt = (const float*)d_in[12];         // [1]

    // Workspace: u [B*S,DR] = 4 MB, rp [R,DR] = 256 KB
    float* u  = (float*)d_ws;
    float* rp = u + (size_t)B_ * S_ * DR_;

    float* out       = (float*)d_out;                 // [B,A,DW]
    float* alpha_out = out + (size_t)B_ * A_ * DW_;   // [B,A,S]

    dim3 blk(256);

    gemm_dual_kernel<<<dim3((B_ * S_) / 64, DR_ / 64, 2), blk, 0, stream>>>(
        qv, Wq, u, B_ * S_, DR_, DW_, bq, bc, cov, Wc,
        rel, Wr, rp, R_, DR_, DR_, br);

    attn_kernel<<<dim3(B_ * (A_ / 4)), blk, 0, stream>>>(
        u, rp, Watt, batt, qv, mask, rsp, out, alpha_out);
}